// Round 10
// baseline (465.976 us; speedup 1.0000x reference)
//
#include <hip/hip_runtime.h>
#include <hip/hip_bf16.h>
#include <cstdint>
#include <cstddef>

#define BB   8
#define NN   4096
#define CC   64
#define KK   16
#define H2   128
#define NPOSF 524288.0f
#define BNEPS 1e-5f

typedef __attribute__((ext_vector_type(8))) short  short8;
typedef __attribute__((ext_vector_type(4))) float  f32x4;

#define MFMA(a,b,c) __builtin_amdgcn_mfma_f32_16x16x32_bf16(a, b, c, 0, 0, 0)

// ---------- helpers ----------
__device__ __forceinline__ unsigned short f2bf(float x) {
  union { float f; unsigned u; } v; v.f = x;
  unsigned u = v.u;
  return (unsigned short)((u + 0x7fffu + ((u >> 16) & 1u)) >> 16);
}
__device__ __forceinline__ float bf2f(unsigned short h) {
  union { unsigned u; float f; } v; v.u = ((unsigned)h) << 16; return v.f;
}

// ---------- utility kernels ----------
// pos2t[b][n] = (x,y,z, x^2+y^2+z^2) — PINNED to np rounding
__global__ __launch_bounds__(256) void k_pos2t(const float* __restrict__ pos2, float4* __restrict__ out) {
  int i = blockIdx.x * 256 + threadIdx.x;
  int b = i >> 12, n = i & 4095;
  float x = pos2[(b*3 + 0)*NN + n];
  float y = pos2[(b*3 + 1)*NN + n];
  float z = pos2[(b*3 + 2)*NN + n];
  float w = __fadd_rn(__fadd_rn(__fmul_rn(x,x), __fmul_rn(y,y)), __fmul_rn(z,z));
  out[i] = make_float4(x, y, z, w);
}

// [B,64,N] fp32 -> [B,N,64] bf16
__global__ __launch_bounds__(256) void k_transposeb(const float* __restrict__ in, unsigned short* __restrict__ out) {
  __shared__ float tile[32][33];
  int b = blockIdx.z;
  int n0 = blockIdx.x * 32, c0 = blockIdx.y * 32;
  int tx = threadIdx.x, ty = threadIdx.y;
  #pragma unroll
  for (int i = 0; i < 32; i += 8)
    tile[ty + i][tx] = in[((size_t)(b*CC + c0 + ty + i))*NN + n0 + tx];
  __syncthreads();
  #pragma unroll
  for (int i = 0; i < 32; i += 8)
    out[((size_t)(b*NN + n0 + ty + i))*CC + c0 + tx] = f2bf(tile[tx][ty + i]);
}

// ---------- weight pre-pack (A-fragment order, hi bf16) + stats zeroing ----------
// A[m=lane&15][k=quad*8+j] per mfma_f32_16x16x32_bf16. Layer0 channel reorder:
// c'<128 -> orig c'+3 (f2 then f1), c'=128..130 -> pos_diff, pad->0.
// Grid = 64 blocks: all blocks zero their stats chunk; blocks 0..10 also pack W.
__global__ __launch_bounds__(256) void k_wt(const float* __restrict__ W0, const float* __restrict__ W1,
                                            const float* __restrict__ W2, unsigned short* __restrict__ Apk0,
                                            unsigned short* __restrict__ Apk1, unsigned short* __restrict__ Apk2,
                                            float* __restrict__ statsz) {
  int i = blockIdx.x * 256 + threadIdx.x;
  statsz[i] = 0.f;                     // 64*256 = 16384 floats
  if (i < 1280) {            // L0: 4 mt x 5 s x 64 lanes
    int mt = i / 320, r = i % 320, s = r / 64, lane = r % 64;
    int o = mt*16 + (lane & 15), q = lane >> 4, fi = mt*5 + s;
    #pragma unroll
    for (int j = 0; j < 8; ++j) {
      int c = s*32 + q*8 + j;
      float w = 0.f;
      if (c < 131) { int cs = (c < 128) ? (c + 3) : (c - 128); w = W0[o*131 + cs]; }
      Apk0[((size_t)(fi)*64 + lane)*8 + j] = f2bf(w);
    }
  } else if (i < 1792) {     // L1: 4 mt x 2 s
    int k = i - 1280, mt = k / 128, r = k % 128, s = r / 64, lane = r % 64;
    int o = mt*16 + (lane & 15), q = lane >> 4, fi = mt*2 + s;
    #pragma unroll
    for (int j = 0; j < 8; ++j) {
      int c = s*32 + q*8 + j;
      Apk1[((size_t)(fi)*64 + lane)*8 + j] = f2bf(W1[o*64 + c]);
    }
  } else if (i < 2816) {     // L2: 8 mt x 2 s
    int k = i - 1792, mt = k / 128, r = k % 128, s = r / 64, lane = r % 64;
    int o = mt*16 + (lane & 15), q = lane >> 4, fi = mt*2 + s;
    #pragma unroll
    for (int j = 0; j < 8; ++j) {
      int c = s*32 + q*8 + j;
      Apk2[((size_t)(fi)*64 + lane)*8 + j] = f2bf(W2[o*64 + c]);
    }
  }
}

// ---------- KNN: 4 queries/wave (16-lane subgroups), lane-distributed sorted top-16 ----------
// Set-exactness invariants (HW-validated R6-R9): exact _rn distance expression (np op
// order), candidates processed in ascending ref index, strict < vs tau rejects equal-d
// later indices, strict > displacement keeps earlier index first. DPP row_shr:1 operates
// within 16-lane rows == subgroups, so one instruction does 4 independent inserts.
__global__ __launch_bounds__(256) void k_knn(const float* __restrict__ pos1_re,
                                             const float4* __restrict__ pos2t,
                                             unsigned short* __restrict__ idxOut) {
  const int t = threadIdx.x;
  const int lane = t & 63;
  const int wv = t >> 6;             // 4 waves/block
  const int sg = lane >> 4;          // subgroup 0..3
  const int sl = lane & 15;          // lane within subgroup = rank
  const int b = blockIdx.y;
  const int n = blockIdx.x*16 + wv*4 + sg;   // query id (subgroup-uniform)

  const float qx = pos1_re[(b*3 + 0)*NN + n];
  const float qy = pos1_re[(b*3 + 1)*NN + n];
  const float qz = pos1_re[(b*3 + 2)*NN + n];
  const float q2 = __fadd_rn(__fadd_rn(__fmul_rn(qx,qx), __fmul_rn(qy,qy)), __fmul_rn(qz,qz));

  unsigned bd  = 0xFFFFFFFFu;        // rank-sl key (transformed distance)
  unsigned bix = 0u;                 // rank-sl ref index
  unsigned tau = 0xFFFFFFFFu;        // subgroup's rank-15 key (per-lane copy)

  const float4* rp = pos2t + (size_t)b*NN;
  for (int it = 0; it < 256; ++it) {
    float4 r = rp[it*16 + sl];       // subgroups load same 16 refs (broadcast-friendly)
    float dot = __fadd_rn(__fadd_rn(__fmul_rn(qx,r.x), __fmul_rn(qy,r.y)), __fmul_rn(qz,r.z));
    float d   = __fsub_rn(__fadd_rn(q2, r.w), __fmul_rn(2.0f, dot));
    unsigned du = __float_as_uint(d);
    du ^= (du >> 31) ? 0xFFFFFFFFu : 0x80000000u;   // exact total-order transform

    unsigned long long full = __ballot(du < tau);
    unsigned m16 = (unsigned)(full >> (sg*16)) & 0xFFFFu;
    while (__any(m16 != 0u)) {
      const bool has = (m16 != 0u);
      const int l = __ffs(m16) - 1;               // -1 when empty (predicated off)
      m16 &= (m16 - 1);
      const int srcl = sg*16 + (has ? l : 0);
      const unsigned sd = (unsigned)__shfl((int)du, srcl);
      const bool valid = has && (sd < tau);       // tau may have shrunk since ballot
      const unsigned sidx = (unsigned)(it*16 + l);
      int m = (valid && (bd > sd)) ? 1 : 0;       // strict: equal-d keeps earlier index
      int pm = __builtin_amdgcn_update_dpp(0, m, 0x111, 0xF, 0xF, true);
      unsigned sb = (unsigned)__builtin_amdgcn_update_dpp(0, (int)bd,  0x111, 0xF, 0xF, true);
      unsigned si = (unsigned)__builtin_amdgcn_update_dpp(0, (int)bix, 0x111, 0xF, 0xF, true);
      if (m) { bd = pm ? sb : sd; bix = pm ? si : sidx; }
      tau = (unsigned)__shfl((int)bd, sg*16 + 15);
    }
  }

  idxOut[((size_t)(b*NN + n))*KK + sl] = (unsigned short)bix;
}

// ---------- wave-level deferred stat reduce (once per wave) ----------
#define WAVE_STATS(NMT) { \
  _Pragma("unroll") \
  for (int mt = 0; mt < NMT; ++mt) { \
    _Pragma("unroll") \
    for (int rg = 0; rg < 4; ++rg) { \
      float s_ = sacc[mt][rg], q_ = sqacc[mt][rg]; \
      s_ += __shfl_xor(s_,1); s_ += __shfl_xor(s_,2); s_ += __shfl_xor(s_,4); s_ += __shfl_xor(s_,8); \
      q_ += __shfl_xor(q_,1); q_ += __shfl_xor(q_,2); q_ += __shfl_xor(q_,4); q_ += __shfl_xor(q_,8); \
      if (cl == 0) { atomicAdd(&sS[mt*16 + q*4 + rg], s_); atomicAdd(&sQ[mt*16 + q*4 + rg], q_); } \
    } \
  } }

// ---------- layer 0: gather -> MFMA(64 x 160K), reg weights, no LDS staging ----------
__global__ __launch_bounds__(256) void k_layer0(
    const unsigned short* __restrict__ nidx, const float4* __restrict__ pos2t,
    const float* __restrict__ pos1, const unsigned short* __restrict__ f2b,
    const unsigned short* __restrict__ f1b, const unsigned short* __restrict__ Apk0,
    unsigned short* __restrict__ Y0, float* __restrict__ gS, float* __restrict__ gQ) {
  __shared__ float sS[64], sQ[64];
  const int t = threadIdx.x, lane = t & 63, wv = t >> 6;
  const int b = blockIdx.y, n0 = blockIdx.x*32 + wv*8;
  const int cl = lane & 15, q = lane >> 4;

  short8 Wr[20];
  #pragma unroll
  for (int f = 0; f < 20; ++f) Wr[f] = *(const short8*)(Apk0 + ((size_t)f*64 + lane)*8);
  if (t < 64) { sS[t] = 0.f; sQ[t] = 0.f; }
  __syncthreads();

  f32x4 sacc[4]  = {{0,0,0,0},{0,0,0,0},{0,0,0,0},{0,0,0,0}};
  f32x4 sqacc[4] = {{0,0,0,0},{0,0,0,0},{0,0,0,0},{0,0,0,0}};

  #pragma unroll 1
  for (int p = 0; p < 8; ++p) {
    const int n = n0 + p;
    const int m = (int)nidx[((size_t)(b*NN + n))*KK + cl];
    const unsigned short* f2r = f2b + ((size_t)(b*NN + m))*64;
    const unsigned short* f1r = f1b + ((size_t)(b*NN + n))*64;
    short8 x0 = *(const short8*)(f2r + q*8);
    short8 x1 = *(const short8*)(f2r + 32 + q*8);
    short8 x2 = *(const short8*)(f1r + q*8);
    short8 x3 = *(const short8*)(f1r + 32 + q*8);
    short8 x4 = {0,0,0,0,0,0,0,0};
    if (q == 0) {
      float4 pp = pos2t[(size_t)b*NN + m];
      float px = pos1[(b*3 + 0)*NN + n];
      float py = pos1[(b*3 + 1)*NN + n];
      float pz = pos1[(b*3 + 2)*NN + n];
      x4[0] = (short)f2bf(pp.x - px);
      x4[1] = (short)f2bf(pp.y - py);
      x4[2] = (short)f2bf(pp.z - pz);
    }
    f32x4 acc[4] = {{0,0,0,0},{0,0,0,0},{0,0,0,0},{0,0,0,0}};
    #pragma unroll
    for (int mt = 0; mt < 4; ++mt) {
      acc[mt] = MFMA(Wr[mt*5 + 0], x0, acc[mt]);
      acc[mt] = MFMA(Wr[mt*5 + 1], x1, acc[mt]);
      acc[mt] = MFMA(Wr[mt*5 + 2], x2, acc[mt]);
      acc[mt] = MFMA(Wr[mt*5 + 3], x3, acc[mt]);
      acc[mt] = MFMA(Wr[mt*5 + 4], x4, acc[mt]);
    }
    unsigned short* yr = Y0 + (((size_t)(b*NN + n))*KK + cl)*64;
    #pragma unroll
    for (int mt = 0; mt < 4; ++mt) {
      sacc[mt]  += acc[mt];
      sqacc[mt] += acc[mt]*acc[mt];
      ushort4 pk; pk.x = f2bf(acc[mt][0]); pk.y = f2bf(acc[mt][1]);
      pk.z = f2bf(acc[mt][2]); pk.w = f2bf(acc[mt][3]);
      *(ushort4*)(yr + mt*16 + q*4) = pk;
    }
  }
  WAVE_STATS(4)
  __syncthreads();
  const int slot = blockIdx.x & 31;
  if (t < 64) { atomicAdd(&gS[slot*64 + t], sS[t]); atomicAdd(&gQ[slot*64 + t], sQ[t]); }
}

// ---------- finalize BN stats (sum 32 copies) ----------
__global__ __launch_bounds__(128) void k_finalize(const float* __restrict__ S, const float* __restrict__ Q,
                                                  const float* __restrict__ g, const float* __restrict__ bb_,
                                                  float* __restrict__ A, float* __restrict__ Bt, int ch) {
  int t = threadIdx.x;
  if (t < ch) {
    float s = 0.f, qq = 0.f;
    for (int c = 0; c < 32; ++c) { s += S[c*ch + t]; qq += Q[c*ch + t]; }
    float mean = s * (1.0f / NPOSF);
    float var  = qq * (1.0f / NPOSF) - mean*mean;
    float rs   = 1.0f / sqrtf(var + BNEPS);
    float a    = g[t] * rs;
    A[t] = a; Bt[t] = bb_[t] - mean*a;
  }
}

// ---------- layer 1: bn0+relu(Y0) -> MFMA(64x64), reg weights ----------
__global__ __launch_bounds__(256) void k_layer1(
    const unsigned short* __restrict__ Y0, const float* __restrict__ A0, const float* __restrict__ B0,
    const unsigned short* __restrict__ Apk1, unsigned short* __restrict__ Y1,
    float* __restrict__ gS, float* __restrict__ gQ) {
  __shared__ float sS[64], sQ[64];
  const int t = threadIdx.x, lane = t & 63, wv = t >> 6;
  const int b = blockIdx.y, n0 = blockIdx.x*32 + wv*8;
  const int cl = lane & 15, q = lane >> 4;

  short8 Wr[8];
  #pragma unroll
  for (int f = 0; f < 8; ++f) Wr[f] = *(const short8*)(Apk1 + ((size_t)f*64 + lane)*8);
  float ar[16], br[16];
  #pragma unroll
  for (int s = 0; s < 2; ++s)
    #pragma unroll
    for (int j = 0; j < 8; ++j) { int c = s*32 + q*8 + j; ar[s*8+j] = A0[c]; br[s*8+j] = B0[c]; }
  if (t < 64) { sS[t] = 0.f; sQ[t] = 0.f; }
  __syncthreads();

  f32x4 sacc[4]  = {{0,0,0,0},{0,0,0,0},{0,0,0,0},{0,0,0,0}};
  f32x4 sqacc[4] = {{0,0,0,0},{0,0,0,0},{0,0,0,0},{0,0,0,0}};

  #pragma unroll 1
  for (int p = 0; p < 8; ++p) {
    const int n = n0 + p;
    const unsigned short* yr = Y0 + (((size_t)(b*NN + n))*KK + cl)*64;
    short8 u0 = *(const short8*)(yr + q*8);
    short8 u1 = *(const short8*)(yr + 32 + q*8);
    short8 x0, x1;
    #pragma unroll
    for (int j = 0; j < 8; ++j) {
      x0[j] = (short)f2bf(fmaxf(bf2f((unsigned short)u0[j])*ar[j]   + br[j],   0.f));
      x1[j] = (short)f2bf(fmaxf(bf2f((unsigned short)u1[j])*ar[8+j] + br[8+j], 0.f));
    }
    f32x4 acc[4] = {{0,0,0,0},{0,0,0,0},{0,0,0,0},{0,0,0,0}};
    #pragma unroll
    for (int mt = 0; mt < 4; ++mt) {
      acc[mt] = MFMA(Wr[mt*2 + 0], x0, acc[mt]);
      acc[mt] = MFMA(Wr[mt*2 + 1], x1, acc[mt]);
    }
    unsigned short* yw = Y1 + (((size_t)(b*NN + n))*KK + cl)*64;
    #pragma unroll
    for (int mt = 0; mt < 4; ++mt) {
      sacc[mt]  += acc[mt];
      sqacc[mt] += acc[mt]*acc[mt];
      ushort4 pk; pk.x = f2bf(acc[mt][0]); pk.y = f2bf(acc[mt][1]);
      pk.z = f2bf(acc[mt][2]); pk.w = f2bf(acc[mt][3]);
      *(ushort4*)(yw + mt*16 + q*4) = pk;
    }
  }
  WAVE_STATS(4)
  __syncthreads();
  const int slot = blockIdx.x & 31;
  if (t < 64) { atomicAdd(&gS[slot*64 + t], sS[t]); atomicAdd(&gQ[slot*64 + t], sQ[t]); }
}

// ---------- layer 2 stats: bn1+relu(Y1) -> MFMA(128x64) -> stats ----------
__global__ __launch_bounds__(256) void k_l2stats(
    const unsigned short* __restrict__ Y1, const float* __restrict__ A1, const float* __restrict__ B1,
    const unsigned short* __restrict__ Apk2, float* __restrict__ gS, float* __restrict__ gQ) {
  __shared__ float sS[128], sQ[128];
  const int t = threadIdx.x, lane = t & 63, wv = t >> 6;
  const int b = blockIdx.y, n0 = blockIdx.x*32 + wv*8;
  const int cl = lane & 15, q = lane >> 4;

  short8 Wr[16];
  #pragma unroll
  for (int f = 0; f < 16; ++f) Wr[f] = *(const short8*)(Apk2 + ((size_t)f*64 + lane)*8);
  float ar[16], br[16];
  #pragma unroll
  for (int s = 0; s < 2; ++s)
    #pragma unroll
    for (int j = 0; j < 8; ++j) { int c = s*32 + q*8 + j; ar[s*8+j] = A1[c]; br[s*8+j] = B1[c]; }
  if (t < 128) { sS[t] = 0.f; sQ[t] = 0.f; }
  __syncthreads();

  f32x4 sacc[8]  = {{0,0,0,0},{0,0,0,0},{0,0,0,0},{0,0,0,0},{0,0,0,0},{0,0,0,0},{0,0,0,0},{0,0,0,0}};
  f32x4 sqacc[8] = {{0,0,0,0},{0,0,0,0},{0,0,0,0},{0,0,0,0},{0,0,0,0},{0,0,0,0},{0,0,0,0},{0,0,0,0}};

  #pragma unroll 1
  for (int p = 0; p < 8; ++p) {
    const int n = n0 + p;
    const unsigned short* yr = Y1 + (((size_t)(b*NN + n))*KK + cl)*64;
    short8 u0 = *(const short8*)(yr + q*8);
    short8 u1 = *(const short8*)(yr + 32 + q*8);
    short8 x0, x1;
    #pragma unroll
    for (int j = 0; j < 8; ++j) {
      x0[j] = (short)f2bf(fmaxf(bf2f((unsigned short)u0[j])*ar[j]   + br[j],   0.f));
      x1[j] = (short)f2bf(fmaxf(bf2f((unsigned short)u1[j])*ar[8+j] + br[8+j], 0.f));
    }
    #pragma unroll
    for (int mt = 0; mt < 8; ++mt) {
      f32x4 acc = {0,0,0,0};
      acc = MFMA(Wr[mt*2 + 0], x0, acc);
      acc = MFMA(Wr[mt*2 + 1], x1, acc);
      sacc[mt]  += acc;
      sqacc[mt] += acc*acc;
    }
  }
  WAVE_STATS(8)
  __syncthreads();
  const int slot = blockIdx.x & 31;
  if (t < 128) { atomicAdd(&gS[slot*128 + t], sS[t]); atomicAdd(&gQ[slot*128 + t], sQ[t]); }
}

// ---------- layer 2 final: recompute y2, bn2+relu+max over k -> out ----------
__global__ __launch_bounds__(256) void k_l2final(
    const unsigned short* __restrict__ Y1, const float* __restrict__ A1, const float* __restrict__ B1,
    const unsigned short* __restrict__ Apk2, const float* __restrict__ A2, const float* __restrict__ B2,
    float* __restrict__ outF) {
  __shared__ float a2s[128], b2s[128];
  __shared__ float oBuf[32*128];                           // 16 KB [np][ch]
  const int t = threadIdx.x, lane = t & 63, wv = t >> 6;
  const int b = blockIdx.y, n0 = blockIdx.x*32 + wv*8;
  const int cl = lane & 15, q = lane >> 4;

  short8 Wr[16];
  #pragma unroll
  for (int f = 0; f < 16; ++f) Wr[f] = *(const short8*)(Apk2 + ((size_t)f*64 + lane)*8);
  float ar[16], br[16];
  #pragma unroll
  for (int s = 0; s < 2; ++s)
    #pragma unroll
    for (int j = 0; j < 8; ++j) { int c = s*32 + q*8 + j; ar[s*8+j] = A1[c]; br[s*8+j] = B1[c]; }
  if (t < 128) { a2s[t] = A2[t]; b2s[t] = B2[t]; }
  __syncthreads();

  #pragma unroll 1
  for (int p = 0; p < 8; ++p) {
    const int n = n0 + p;
    const unsigned short* yr = Y1 + (((size_t)(b*NN + n))*KK + cl)*64;
    short8 u0 = *(const short8*)(yr + q*8);
    short8 u1 = *(const short8*)(yr + 32 + q*8);
    short8 x0, x1;
    #pragma unroll
    for (int j = 0; j < 8; ++j) {
      x0[j] = (short)f2bf(fmaxf(bf2f((unsigned short)u0[j])*ar[j]   + br[j],   0.f));
      x1[j] = (short)f2bf(fmaxf(bf2f((unsigned short)u1[j])*ar[8+j] + br[8+j], 0.f));
    }
    const int np = wv*8 + p;
    #pragma unroll
    for (int mt = 0; mt < 8; ++mt) {
      f32x4 acc = {0,0,0,0};
      acc = MFMA(Wr[mt*2 + 0], x0, acc);
      acc = MFMA(Wr[mt*2 + 1], x1, acc);
      #pragma unroll
      for (int rg = 0; rg < 4; ++rg) {
        int ch = mt*16 + q*4 + rg;
        float v = fmaxf(acc[rg]*a2s[ch] + b2s[ch], 0.f);
        v = fmaxf(v, __shfl_xor(v, 1));
        v = fmaxf(v, __shfl_xor(v, 2));
        v = fmaxf(v, __shfl_xor(v, 4));
        v = fmaxf(v, __shfl_xor(v, 8));
        if (cl == 0) oBuf[np*128 + ch] = v;
      }
    }
  }
  __syncthreads();
  {
    const int ch = t & 127, npb = (t >> 7) * 16;
    const int nb = blockIdx.x*32;
    #pragma unroll
    for (int g = 0; g < 4; ++g) {
      float4 v = make_float4(oBuf[(npb + g*4 + 0)*128 + ch],
                             oBuf[(npb + g*4 + 1)*128 + ch],
                             oBuf[(npb + g*4 + 2)*128 + ch],
                             oBuf[(npb + g*4 + 3)*128 + ch]);
      *(float4*)(outF + ((size_t)(b*H2 + ch))*NN + nb + npb + g*4) = v;
    }
  }
}

// ---------- launch ----------
extern "C" void kernel_launch(void* const* d_in, const int* in_sizes, int n_in,
                              void* d_out, int out_size, void* d_ws, size_t ws_size,
                              hipStream_t stream) {
  const float* pos1    = (const float*)d_in[0];
  const float* pos1_re = (const float*)d_in[1];
  const float* pos2    = (const float*)d_in[2];
  const float* f1      = (const float*)d_in[3];
  const float* f2      = (const float*)d_in[4];
  const float* W0 = (const float*)d_in[6];
  const float* g0 = (const float*)d_in[7];
  const float* b0 = (const float*)d_in[8];
  const float* W1 = (const float*)d_in[9];
  const float* g1 = (const float*)d_in[10];
  const float* b1 = (const float*)d_in[11];
  const float* W2 = (const float*)d_in[12];
  const float* g2 = (const float*)d_in[13];
  const float* b2 = (const float*)d_in[14];
  float* out = (float*)d_out;

  // workspace layout (bytes)
  char* ws = (char*)d_ws;
  float* stats = (float*)ws;                 // 65536 B
  float* S0 = stats;         float* Q0 = stats + 2048;
  float* S1 = stats + 4096;  float* Q1 = stats + 6144;
  float* S2 = stats + 8192;  float* Q2 = stats + 12288;
  float* prm = (float*)(ws + 65536);         // 2048 B
  float* A0 = prm;       float* B0a = prm + 64;
  float* A1 = prm + 128; float* B1a = prm + 192;
  float* A2 = prm + 256; float* B2a = prm + 384;
  unsigned short* Apk0 = (unsigned short*)(ws + 67584);    // 20480 B used
  unsigned short* Apk1 = (unsigned short*)(ws + 108544);   // 8192 B used
  unsigned short* Apk2 = (unsigned short*)(ws + 124928);   // 16384 B used
  unsigned short* idxb = (unsigned short*)(ws + 157696);   // 1 MB
  float4* pos2t        = (float4*)(ws + 1206272);          // 512 KB
  unsigned short* f2b  = (unsigned short*)(ws + 1730560);  // 4 MB
  unsigned short* f1b  = (unsigned short*)(ws + 5924864);  // 4 MB
  unsigned short* Y0   = (unsigned short*)(ws + 10119168); // 64 MB
  unsigned short* Y1   = (unsigned short*)(ws + 77228032); // 64 MB -> 144336896
  if (ws_size < 144336896u) return;

  k_wt<<<dim3(64), 256, 0, stream>>>(W0, W1, W2, Apk0, Apk1, Apk2, stats);
  hipMemcpyAsync(out, pos1, (size_t)BB*3*NN*sizeof(float), hipMemcpyDeviceToDevice, stream);

  k_pos2t<<<dim3(BB*NN/256), 256, 0, stream>>>(pos2, pos2t);
  k_transposeb<<<dim3(NN/32, CC/32, BB), dim3(32, 8), 0, stream>>>(f2, f2b);
  k_transposeb<<<dim3(NN/32, CC/32, BB), dim3(32, 8), 0, stream>>>(f1, f1b);
  k_knn<<<dim3(NN/16, BB), 256, 0, stream>>>(pos1_re, pos2t, idxb);

  k_layer0<<<dim3(NN/32, BB), 256, 0, stream>>>(idxb, pos2t, pos1, f2b, f1b, Apk0, Y0, S0, Q0);
  k_finalize<<<1, 128, 0, stream>>>(S0, Q0, g0, b0, A0, B0a, 64);

  k_layer1<<<dim3(NN/32, BB), 256, 0, stream>>>(Y0, A0, B0a, Apk1, Y1, S1, Q1);
  k_finalize<<<1, 128, 0, stream>>>(S1, Q1, g1, b1, A1, B1a, 64);

  k_l2stats<<<dim3(NN/32, BB), 256, 0, stream>>>(Y1, A1, B1a, Apk2, S2, Q2);
  k_finalize<<<1, 128, 0, stream>>>(S2, Q2, g2, b2, A2, B2a, 128);

  k_l2final<<<dim3(NN/32, BB), 256, 0, stream>>>(Y1, A1, B1a, Apk2, A2, B2a, out + (size_t)BB*3*NN);
}